// Round 4
// baseline (569.778 us; speedup 1.0000x reference)
//
#include <hip/hip_runtime.h>
#include <hip/hip_bf16.h>
#include <stdint.h>

// Problem constants (fixed by the reference)
#define B_DIM 4
#define S_DIM 2048
#define DIN   4096
#define DOUT  4096
#define M_TOT (B_DIM * S_DIM)   // 8192

typedef __attribute__((ext_vector_type(8))) short  bf16x8;  // 8 bf16 = 4 VGPRs
typedef __attribute__((ext_vector_type(4))) float  f32x4;   // 4 fp32 acc
typedef __attribute__((ext_vector_type(8))) unsigned short u16x8;
typedef __attribute__((ext_vector_type(4))) float  float4v;

__device__ __forceinline__ unsigned short f2b(float f) {
  // round-to-nearest-even bf16
  union { float f; unsigned int i; } v; v.f = f;
  unsigned int r = v.i + 0x7FFFu + ((v.i >> 16) & 1u);
  return (unsigned short)(r >> 16);
}

// ---------------------------------------------------------------------------
// Kernel 1: wb = bf16( aa * tanh(kk * w) ), fp32 -> bf16, into ws[0..32MB).
// ---------------------------------------------------------------------------
__global__ void wb_tanh_kernel(const float4v* __restrict__ w, u16x8* __restrict__ wb,
                               const float* __restrict__ kk,
                               const float* __restrict__ aa, int n8) {
  const float k = kk[0];
  const float a = aa[0];
  int i = blockIdx.x * blockDim.x + threadIdx.x;
  const int stride = gridDim.x * blockDim.x;
  for (; i < n8; i += stride) {
    float4v v0 = w[2 * i];
    float4v v1 = w[2 * i + 1];
    u16x8 o;
#pragma unroll
    for (int j = 0; j < 4; ++j) o[j]     = f2b(a * tanhf(k * v0[j]));
#pragma unroll
    for (int j = 0; j < 4; ++j) o[j + 4] = f2b(a * tanhf(k * v1[j]));
    wb[i] = o;
  }
}

// ---------------------------------------------------------------------------
// Kernel 2: xb = bf16(x), fp32 -> bf16, into ws[32MB..96MB).
// ---------------------------------------------------------------------------
__global__ void x_cvt_kernel(const float4v* __restrict__ x, u16x8* __restrict__ xb, int n8) {
  int i = blockIdx.x * blockDim.x + threadIdx.x;
  const int stride = gridDim.x * blockDim.x;
  for (; i < n8; i += stride) {
    float4v v0 = x[2 * i];
    float4v v1 = x[2 * i + 1];
    u16x8 o;
#pragma unroll
    for (int j = 0; j < 4; ++j) o[j]     = f2b(v0[j]);
#pragma unroll
    for (int j = 0; j < 4; ++j) o[j + 4] = f2b(v1[j]);
    xb[i] = o;
  }
}

// ---------------------------------------------------------------------------
// Kernel 3: C[M,N] = Xb[M,K] * Wb[N,K]^T + bias, bf16 in / FP32 OUT, fp32 acc.
// m97-structure: 128x128 block tile, BK=32, 4 waves (2x2), each wave 4x4 of
// 16x16x32 bf16 MFMAs. Staging via global_load_lds width=16.
// (Staging/fragment/epilogue math verified by rounds 2&3 producing bit-
//  identical outputs via two independent staging paths; only the output
//  dtype was wrong — fixed here: C is float*.)
// ---------------------------------------------------------------------------
#define BM 128
#define BN 128
#define BK 32

__device__ __forceinline__ void glds16(const void* g, void* l) {
  __builtin_amdgcn_global_load_lds(
      (const __attribute__((address_space(1))) void*)g,
      (__attribute__((address_space(3))) void*)l,
      16, 0, 0);
}

__global__ __launch_bounds__(256, 3)
void gemm_bt_bias_kernel(const unsigned short* __restrict__ A,    // [M_TOT, DIN] bf16 bits
                         const unsigned short* __restrict__ Bw,   // [DOUT, DIN] bf16 bits (w_b)
                         const float* __restrict__ bias,          // [DOUT] fp32
                         float* __restrict__ C) {                 // [M_TOT, DOUT] fp32
  __shared__ unsigned short As[BM * BK];  // 8 KB, row-major 128x32, unpadded (glds layout)
  __shared__ unsigned short Bs[BN * BK];  // 8 KB

  const int tid  = threadIdx.x;
  const int wave = tid >> 6;   // 0..3
  const int lane = tid & 63;

  const int bm = blockIdx.y * BM;
  const int bn = blockIdx.x * BN;

  // --- staging addressing ---
  // One glds16 per wave writes 64 lanes * 16B = 1024B = 16 rows of 32 bf16.
  // Lane l -> LDS byte base + 16*l -> row base_row + (l>>2), col elems (l&3)*8.
  const int l4 = lane >> 2;
  const int lc = (lane & 3) * 8;
  const unsigned short* aG = A  + (size_t)(bm + wave * 32 + l4) * DIN + lc;
  const unsigned short* bG = Bw + (size_t)(bn + wave * 32 + l4) * DIN + lc;
  unsigned short* aL = &As[wave * 2 * 512];  // wave-uniform LDS base
  unsigned short* bL = &Bs[wave * 2 * 512];

  // --- compute addressing ---
  // Wave (2x2): wave>>1 -> 64-row half, wave&1 -> 64-col half.
  // A-frag: A[m = lane&15][k = quad*8 + j]  (ds_read_b128)
  // B-frag: Wb[n = lane&15][k = quad*8 + j] (Bw is B^T: same pattern)
  // C/D:    col = lane&15, row = quad*4 + reg   [m89 mapping]
  const int wm   = (wave >> 1) * 64;
  const int wn   = (wave & 1) * 64;
  const int quad = lane >> 4;
  const int r    = lane & 15;

  f32x4 acc[4][4] = {};

  for (int k0 = 0; k0 < DIN; k0 += BK) {
    glds16(aG,            aL);
    glds16(aG + 16 * DIN, aL + 512);
    glds16(bG,            bL);
    glds16(bG + 16 * DIN, bL + 512);
    aG += BK; bG += BK;
    __syncthreads();   // drains vmcnt (glds writes land) before LDS reads

    bf16x8 af[4], bfr[4];
#pragma unroll
    for (int mi = 0; mi < 4; ++mi)
      af[mi] = *(const bf16x8*)&As[(wm + mi * 16 + r) * BK + quad * 8];
#pragma unroll
    for (int ni = 0; ni < 4; ++ni)
      bfr[ni] = *(const bf16x8*)&Bs[(wn + ni * 16 + r) * BK + quad * 8];

#pragma unroll
    for (int mi = 0; mi < 4; ++mi)
#pragma unroll
      for (int ni = 0; ni < 4; ++ni)
        acc[mi][ni] = __builtin_amdgcn_mfma_f32_16x16x32_bf16(
            af[mi], bfr[ni], acc[mi][ni], 0, 0, 0);

    __syncthreads();   // all LDS reads done before next stage overwrites
  }

  // --- epilogue: bias add + FP32 store ---
#pragma unroll
  for (int ni = 0; ni < 4; ++ni) {
    const int col = bn + wn + ni * 16 + r;
    const float bv = bias[col];
#pragma unroll
    for (int mi = 0; mi < 4; ++mi) {
      const int row0 = bm + wm + mi * 16 + quad * 4;
#pragma unroll
      for (int e = 0; e < 4; ++e) {
        C[(size_t)(row0 + e) * DOUT + col] = acc[mi][ni][e] + bv;
      }
    }
  }
}

// ---------------------------------------------------------------------------
extern "C" void kernel_launch(void* const* d_in, const int* in_sizes, int n_in,
                              void* d_out, int out_size, void* d_ws, size_t ws_size,
                              hipStream_t stream) {
  // setup_inputs order: x, weight, bias, kk, aa (fp32); OUTPUT fp32 (reference dtype)
  const float* x    = (const float*)d_in[0];  // [8192, 4096] fp32
  const float* w    = (const float*)d_in[1];  // [4096, 4096] fp32
  const float* bias = (const float*)d_in[2];  // [4096] fp32
  const float* kk   = (const float*)d_in[3];  // [1] fp32
  const float* aa   = (const float*)d_in[4];  // [1] fp32
  float* out = (float*)d_out;                 // [8192, 4096] fp32

  // ws layout: wb bf16 [4096,4096] at 0 (32 MB), xb bf16 [8192,4096] at +32MB (64 MB)
  unsigned short* wb = (unsigned short*)d_ws;
  unsigned short* xb = wb + (size_t)DOUT * DIN;

  wb_tanh_kernel<<<2048, 256, 0, stream>>>(
      (const float4v*)w, (u16x8*)wb, kk, aa, DOUT * DIN / 8);
  x_cvt_kernel<<<4096, 256, 0, stream>>>(
      (const float4v*)x, (u16x8*)xb, M_TOT * DIN / 8);

  dim3 grid(DOUT / BN, M_TOT / BM);  // (32, 64) = 2048 blocks
  gemm_bt_bias_kernel<<<grid, 256, 0, stream>>>(xb, wb, bias, out);
}